// Round 7
// baseline (605.203 us; speedup 1.0000x reference)
//
#include <hip/hip_runtime.h>
#include <hip/hip_bf16.h>
#include <math.h>

namespace {
constexpr int kD = 256;      // embed dim
constexpr int kDOUT = 256;   // out dim
constexpr int kNQ = 65536;   // num query nodes
constexpr int kE = 262144;   // edges
constexpr float kAlpha = 0.2f;
constexpr float kEps = 1e-12f;
constexpr int kBins = 2048;  // query bins
constexpr int kQPB = 32;     // queries per bin = kNQ / kBins
}

typedef short bf16x8 __attribute__((ext_vector_type(8)));
typedef float f32x4 __attribute__((ext_vector_type(4)));

static __device__ __forceinline__ float bf2f(ushort u) {
  union { unsigned int i; float f; } v;
  v.i = ((unsigned int)u) << 16;
  return v.f;
}

// c[j] = sum_k a[k][j] * a2[k]   (a is (DOUT, 2D) row-major; j in [0, 512))
__global__ void compute_c_kernel(const float* __restrict__ a,
                                 const float* __restrict__ a2,
                                 float* __restrict__ c) {
  const int j = blockIdx.x * blockDim.x + threadIdx.x;  // 0..511
  float s = 0.f;
#pragma unroll 8
  for (int k = 0; k < kDOUT; ++k) s = fmaf(a[k * (2 * kD) + j], a2[k], s);
  c[j] = s;
}

// zero rowsum[NQ] + bincnt[kBins] (contiguous)
__global__ void zero_kernel(int4* __restrict__ p) {
  p[blockIdx.x * 256 + threadIdx.x] = int4{0, 0, 0, 0};
}

// trans (256x256 f32) -> bf16
__global__ void cvt_trans_kernel(const float* __restrict__ t, ushort* __restrict__ tb) {
  const int i = blockIdx.x * 256 + threadIdx.x;  // 4 elems each
  const float4 v = reinterpret_cast<const float4*>(t)[i];
  union { ushort4 u; __hip_bfloat16 h[4]; } p;
  p.h[0] = __float2bfloat16(v.x);
  p.h[1] = __float2bfloat16(v.y);
  p.h[2] = __float2bfloat16(v.z);
  p.h[3] = __float2bfloat16(v.w);
  reinterpret_cast<ushort4*>(tb)[i] = p.u;
}

// histogram of query bins (LDS-aggregated)
__global__ __launch_bounds__(256) void bin_hist_kernel(const int* __restrict__ qlist,
                                                       int* __restrict__ bincnt) {
  __shared__ int h[kBins];
  for (int i = threadIdx.x; i < kBins; i += 256) h[i] = 0;
  __syncthreads();
  const int i = blockIdx.x * 256 + threadIdx.x;
  const int4 q = reinterpret_cast<const int4*>(qlist)[i];
  atomicAdd(&h[q.x >> 5], 1);
  atomicAdd(&h[q.y >> 5], 1);
  atomicAdd(&h[q.z >> 5], 1);
  atomicAdd(&h[q.w >> 5], 1);
  __syncthreads();
  for (int i2 = threadIdx.x; i2 < kBins; i2 += 256) {
    const int v = h[i2];
    if (v) atomicAdd(&bincnt[i2], v);
  }
}

// single-block exclusive scan of bincnt[kBins] -> binoff, bincur
__global__ __launch_bounds__(1024) void bin_scan_kernel(const int* __restrict__ bincnt,
                                                        int* __restrict__ binoff,
                                                        int* __restrict__ bincur) {
  __shared__ int partial[1024];
  const int t = threadIdx.x;
  const int2 v = reinterpret_cast<const int2*>(bincnt)[t];
  const int s = v.x + v.y;
  partial[t] = s;
  __syncthreads();
  for (int off = 1; off < 1024; off <<= 1) {
    const int p = (t >= off) ? partial[t - off] : 0;
    __syncthreads();
    partial[t] += p;
    __syncthreads();
  }
  int run = partial[t] - s;
  binoff[2 * t] = run; bincur[2 * t] = run; run += v.x;
  binoff[2 * t + 1] = run; bincur[2 * t + 1] = run; run += v.y;
  if (t == 1023) binoff[kBins] = run;  // == E
}

// Pass 1: one wave per edge (sequential read of key/query rows).
// ev = exp(-leaky(key.ck + query.cq)); claim slot in the edge's query-BIN
// (2048 advancing streams -> DRAM-friendly writes); rowsum[q] += ev;
// write bf16(ev*key_row) to wkey[pos] and qloc to bq[pos].
__global__ __launch_bounds__(256) void edge_bin_scatter_kernel(
    const float* __restrict__ key_embed,
    const float* __restrict__ query_embed,
    const int* __restrict__ qlist,
    const float* __restrict__ c,
    int* __restrict__ bincur,
    float* __restrict__ rowsum,
    ushort* __restrict__ wkey,
    int* __restrict__ bq) {
  const int edge = (blockIdx.x << 2) + (threadIdx.x >> 6);
  const int lane = threadIdx.x & 63;

  const float4 k4 = reinterpret_cast<const float4*>(key_embed)[(size_t)edge * (kD / 4) + lane];
  const float4 q4 = reinterpret_cast<const float4*>(query_embed)[(size_t)edge * (kD / 4) + lane];
  const float4 ck = reinterpret_cast<const float4*>(c)[lane];
  const float4 cq = reinterpret_cast<const float4*>(c)[64 + lane];

  float s = k4.x * ck.x + k4.y * ck.y + k4.z * ck.z + k4.w * ck.w
          + q4.x * cq.x + q4.y * cq.y + q4.z * cq.z + q4.w * cq.w;
#pragma unroll
  for (int off = 32; off > 0; off >>= 1) s += __shfl_xor(s, off, 64);

  const float p = (s > 0.f) ? s : kAlpha * s;   // leaky_relu
  const float ev = __expf(-p);

  int pos = 0;
  if (lane == 0) {
    const int q = qlist[edge];
    pos = atomicAdd(&bincur[q >> 5], 1);
    unsafeAtomicAdd(&rowsum[q], ev);
    bq[pos] = q & (kQPB - 1);
  }
  pos = __shfl(pos, 0, 64);

  union { ushort4 u; __hip_bfloat16 h[4]; } pk;
  pk.h[0] = __float2bfloat16(ev * k4.x);
  pk.h[1] = __float2bfloat16(ev * k4.y);
  pk.h[2] = __float2bfloat16(ev * k4.z);
  pk.h[3] = __float2bfloat16(ev * k4.w);
  *reinterpret_cast<ushort4*>(wkey + (size_t)pos * kD + lane * 4) = pk.u;
}

// Pass 2: one block per bin. Sequentially read the bin's weighted rows,
// accumulate into a 32x256 f32 LDS accumulator via ds atomics, then
// normalize by rowsum and write bf16 accb rows.
__global__ __launch_bounds__(256) void bin_reduce_kernel(
    const ushort* __restrict__ wkey,
    const int* __restrict__ bq,
    const int* __restrict__ binoff,
    const float* __restrict__ rowsum,
    ushort* __restrict__ accb) {
  __shared__ float acc[kQPB][kD];
  const int b = blockIdx.x;
  const int tid = threadIdx.x;

  for (int i = tid; i < kQPB * kD / 4; i += 256)
    reinterpret_cast<float4*>(&acc[0][0])[i] = float4{0.f, 0.f, 0.f, 0.f};
  __syncthreads();

  const int wid = tid >> 6;
  const int lane = tid & 63;
  const int s0 = binoff[b], s1 = binoff[b + 1];

  int r = s0 + wid;
  ushort4 ucur = {0, 0, 0, 0};
  int qcur = 0;
  if (r < s1) {
    ucur = *reinterpret_cast<const ushort4*>(wkey + (size_t)r * kD + lane * 4);
    qcur = bq[r];
  }
  while (r < s1) {
    const int rn = r + 4;
    ushort4 unxt = {0, 0, 0, 0};
    int qnxt = 0;
    if (rn < s1) {
      unxt = *reinterpret_cast<const ushort4*>(wkey + (size_t)rn * kD + lane * 4);
      qnxt = bq[rn];
    }
    float* arow = &acc[qcur][lane * 4];
    atomicAdd(&arow[0], bf2f(ucur.x));
    atomicAdd(&arow[1], bf2f(ucur.y));
    atomicAdd(&arow[2], bf2f(ucur.z));
    atomicAdd(&arow[3], bf2f(ucur.w));
    ucur = unxt; qcur = qnxt; r = rn;
  }
  __syncthreads();

  // flush: 8 threads per query, 32 cols each
  const int qloc = tid >> 3;
  const int c0 = (tid & 7) * 32;
  const float rs = rowsum[b * kQPB + qloc];
  const float inv = 1.0f / ((rs == 0.f) ? kEps : rs);
  ushort* orow = accb + (size_t)(b * kQPB + qloc) * kD + c0;
#pragma unroll
  for (int j = 0; j < 32; j += 4) {
    union { ushort4 u; __hip_bfloat16 h[4]; } p;
    p.h[0] = __float2bfloat16(acc[qloc][c0 + j + 0] * inv);
    p.h[1] = __float2bfloat16(acc[qloc][c0 + j + 1] * inv);
    p.h[2] = __float2bfloat16(acc[qloc][c0 + j + 2] * inv);
    p.h[3] = __float2bfloat16(acc[qloc][c0 + j + 3] * inv);
    *reinterpret_cast<ushort4*>(orow + j) = p.u;
  }
}

// out = elu(A @ B^T).  A: (NQ,256) bf16 row-major (pre-normalized), B = trans bf16.
// One wave per 16-row strip, full N=256 in registers (16 n-tiles of 16x16x32 MFMA).
__global__ __launch_bounds__(256) void out_gemm_mfma_kernel(
    const ushort* __restrict__ A,
    const ushort* __restrict__ B,
    float* __restrict__ out) {
  const int wid = threadIdx.x >> 6;
  const int lane = threadIdx.x & 63;
  const int row0 = (blockIdx.x * 4 + wid) * 16;
  const int m = lane & 15;
  const int kb = (lane >> 4) * 8;

  f32x4 acc[16] = {};

  for (int kt = 0; kt < kD; kt += 32) {
    const bf16x8 af = *reinterpret_cast<const bf16x8*>(&A[(size_t)(row0 + m) * kD + kt + kb]);
#pragma unroll
    for (int nt = 0; nt < 16; ++nt) {
      const bf16x8 bf = *reinterpret_cast<const bf16x8*>(&B[(size_t)(nt * 16 + m) * kD + kt + kb]);
      acc[nt] = __builtin_amdgcn_mfma_f32_16x16x32_bf16(af, bf, acc[nt], 0, 0, 0);
    }
  }

#pragma unroll
  for (int nt = 0; nt < 16; ++nt) {
#pragma unroll
    for (int r = 0; r < 4; ++r) {
      const int row = row0 + (lane >> 4) * 4 + r;
      const int col = nt * 16 + (lane & 15);
      const float x = acc[nt][r];
      out[(size_t)row * kDOUT + col] = (x > 0.f) ? x : expm1f(x);
    }
  }
}

extern "C" void kernel_launch(void* const* d_in, const int* in_sizes, int n_in,
                              void* d_out, int out_size, void* d_ws, size_t ws_size,
                              hipStream_t stream) {
  // inputs: 0 key_list(int,E) [unused], 1 key_embed(f32,E*256), 2 query_list(int,E),
  //         3 query_embed(f32,E*256), 4 a(f32,256*512), 5 a_2(f32,256), 6 trans(f32,256*256)
  const float* key_embed = (const float*)d_in[1];
  const int* query_list = (const int*)d_in[2];
  const float* query_embed = (const float*)d_in[3];
  const float* a = (const float*)d_in[4];
  const float* a2 = (const float*)d_in[5];
  const float* trans = (const float*)d_in[6];
  float* out = (float*)d_out;

  // workspace (float units, 16B-aligned):
  // c[512] | rowsum[NQ] | bincnt[kBins] | binoff[kBins+4] | bincur[kBins]
  // | bq[E] | wkey[E*256 ushort] | accb[NQ*256 ushort] | transb[256*256 ushort]
  float* ws = (float*)d_ws;
  float* c = ws;
  float* rowsum = ws + 512;
  int* bincnt = (int*)(rowsum + kNQ);
  int* binoff = bincnt + kBins;
  int* bincur = binoff + kBins + 4;
  int* bq = bincur + kBins;
  float* base2 = (float*)(bq + kE);   // 512+NQ+3*kBins+4+E floats -> multiple of 4
  ushort* wkey = (ushort*)base2;                                  // E*256 bf16
  ushort* accb = (ushort*)(base2 + (size_t)kE * (kD / 2));        // NQ*256 bf16
  ushort* transb = (ushort*)(base2 + (size_t)kE * (kD / 2) + (size_t)kNQ * (kD / 2));

  zero_kernel<<<(kNQ + kBins) / 4 / 256, 256, 0, stream>>>((int4*)rowsum);
  compute_c_kernel<<<2, 256, 0, stream>>>(a, a2, c);
  cvt_trans_kernel<<<kDOUT * kD / 4 / 256, 256, 0, stream>>>(trans, transb);
  bin_hist_kernel<<<kE / 4 / 256, 256, 0, stream>>>(query_list, bincnt);
  bin_scan_kernel<<<1, 1024, 0, stream>>>(bincnt, binoff, bincur);
  edge_bin_scatter_kernel<<<kE / 4, 256, 0, stream>>>(key_embed, query_embed, query_list,
                                                      c, bincur, rowsum, wkey, bq);
  bin_reduce_kernel<<<kBins, 256, 0, stream>>>(wkey, bq, binoff, rowsum, accb);
  out_gemm_mfma_kernel<<<kNQ / 64, 256, 0, stream>>>(accb, transb, out);
}

// Round 8
// 394.282 us; speedup vs baseline: 1.5349x; 1.5349x over previous
//
#include <hip/hip_runtime.h>
#include <hip/hip_bf16.h>
#include <math.h>

namespace {
constexpr int kD = 256;      // embed dim
constexpr int kDOUT = 256;   // out dim
constexpr int kNQ = 65536;   // num query nodes
constexpr int kE = 262144;   // edges
constexpr float kAlpha = 0.2f;
constexpr float kEps = 1e-12f;
}

typedef short bf16x8 __attribute__((ext_vector_type(8)));
typedef float f32x4 __attribute__((ext_vector_type(4)));

static __device__ __forceinline__ float bf2f(ushort u) {
  union { unsigned int i; float f; } v;
  v.i = ((unsigned int)u) << 16;
  return v.f;
}

// c[j] = sum_k a[k][j] * a2[k]   (a is (DOUT, 2D) row-major; j in [0, 512))
__global__ void compute_c_kernel(const float* __restrict__ a,
                                 const float* __restrict__ a2,
                                 float* __restrict__ c) {
  const int j = blockIdx.x * blockDim.x + threadIdx.x;  // 0..511
  float s = 0.f;
#pragma unroll 8
  for (int k = 0; k < kDOUT; ++k) s = fmaf(a[k * (2 * kD) + j], a2[k], s);
  c[j] = s;
}

// zero count[NQ]
__global__ void zero_kernel(int4* __restrict__ p) {
  p[blockIdx.x * 256 + threadIdx.x] = int4{0, 0, 0, 0};
}

// trans (256x256 f32) -> bf16
__global__ void cvt_trans_kernel(const float* __restrict__ t, ushort* __restrict__ tb) {
  const int i = blockIdx.x * 256 + threadIdx.x;  // 4 elems each
  const float4 v = reinterpret_cast<const float4*>(t)[i];
  union { ushort4 u; __hip_bfloat16 h[4]; } p;
  p.h[0] = __float2bfloat16(v.x);
  p.h[1] = __float2bfloat16(v.y);
  p.h[2] = __float2bfloat16(v.z);
  p.h[3] = __float2bfloat16(v.w);
  reinterpret_cast<ushort4*>(tb)[i] = p.u;
}

// histogram of query_list into count[]
__global__ __launch_bounds__(256) void hist_kernel(const int* __restrict__ query_list,
                                                   int* __restrict__ count) {
  const int i = blockIdx.x * 256 + threadIdx.x;
  const int4 q = reinterpret_cast<const int4*>(query_list)[i];
  atomicAdd(&count[q.x], 1);
  atomicAdd(&count[q.y], 1);
  atomicAdd(&count[q.z], 1);
  atomicAdd(&count[q.w], 1);
}

// Single-block exclusive scan of count[NQ] -> offsets, cursor copy.
__global__ __launch_bounds__(1024) void scan_kernel(const int* __restrict__ count,
                                                    int* __restrict__ offsets,
                                                    int* __restrict__ cursor) {
  __shared__ int partial[1024];
  const int t = threadIdx.x;
  int4 loc[16];
#pragma unroll
  for (int i = 0; i < 16; ++i) loc[i] = reinterpret_cast<const int4*>(count)[t * 16 + i];
  int s = 0;
#pragma unroll
  for (int i = 0; i < 16; ++i) s += loc[i].x + loc[i].y + loc[i].z + loc[i].w;
  partial[t] = s;
  __syncthreads();
  for (int off = 1; off < 1024; off <<= 1) {
    int v = (t >= off) ? partial[t - off] : 0;
    __syncthreads();
    partial[t] += v;
    __syncthreads();
  }
  int run = partial[t] - s;
#pragma unroll
  for (int i = 0; i < 16; ++i) {
    const int4 v = loc[i];
    int4 o;
    o.x = run; run += v.x;
    o.y = run; run += v.y;
    o.z = run; run += v.z;
    o.w = run; run += v.w;
    reinterpret_cast<int4*>(offsets)[t * 16 + i] = o;
    reinterpret_cast<int4*>(cursor)[t * 16 + i] = o;
  }
  if (t == 1023) offsets[kNQ] = run;  // == E
}

// Scatter edge ids into CSR order.
__global__ __launch_bounds__(256) void scatter_kernel(const int* __restrict__ query_list,
                                                      int* __restrict__ cursor,
                                                      int* __restrict__ edge_ids) {
  const int edge = blockIdx.x * 256 + threadIdx.x;
  const int q = query_list[edge];
  const int pos = atomicAdd(&cursor[q], 1);
  edge_ids[pos] = edge;
}

// Pass 1: PURE streaming, no atomics. One wave per edge (sequential read).
// ev = exp(-leaky(key.ck + query.cq)); write bf16(ev*key_row) at EDGE order
// (sequential 134MB) and e[edge].
__global__ __launch_bounds__(256) void edge_stream_kernel(
    const float* __restrict__ key_embed,
    const float* __restrict__ query_embed,
    const float* __restrict__ c,
    ushort* __restrict__ wkey,
    float* __restrict__ e_out) {
  const int edge = (blockIdx.x << 2) + (threadIdx.x >> 6);
  const int lane = threadIdx.x & 63;

  const float4 k4 = reinterpret_cast<const float4*>(key_embed)[(size_t)edge * (kD / 4) + lane];
  const float4 q4 = reinterpret_cast<const float4*>(query_embed)[(size_t)edge * (kD / 4) + lane];
  const float4 ck = reinterpret_cast<const float4*>(c)[lane];
  const float4 cq = reinterpret_cast<const float4*>(c)[64 + lane];

  float s = k4.x * ck.x + k4.y * ck.y + k4.z * ck.z + k4.w * ck.w
          + q4.x * cq.x + q4.y * cq.y + q4.z * cq.z + q4.w * cq.w;
#pragma unroll
  for (int off = 32; off > 0; off >>= 1) s += __shfl_xor(s, off, 64);

  const float p = (s > 0.f) ? s : kAlpha * s;   // leaky_relu
  const float ev = __expf(-p);

  union { ushort4 u; __hip_bfloat16 h[4]; } pk;
  pk.h[0] = __float2bfloat16(ev * k4.x);
  pk.h[1] = __float2bfloat16(ev * k4.y);
  pk.h[2] = __float2bfloat16(ev * k4.z);
  pk.h[3] = __float2bfloat16(ev * k4.w);
  *reinterpret_cast<ushort4*>(wkey + (size_t)edge * kD + lane * 4) = pk.u;
  if (lane == 0) e_out[edge] = ev;
}

// Pass 2 (fused segsum + normalize + GEMM + elu).
// One wave per 16 queries. Bulk-preload the wave's CSR edge ids + e values
// lane-parallel; depth-8 pipelined walk over random 512B bf16 rows of wkey
// (L3-resident, 134MB); flush each completed query (normalize + bf16) into a
// per-wave LDS A-tile; then 16x16x32 MFMA against trans (L2) and write out.
__global__ __launch_bounds__(256) void gather_gemm_kernel(
    const ushort* __restrict__ wkey,
    const float* __restrict__ e,
    const int* __restrict__ offsets,
    const int* __restrict__ edge_ids,
    const ushort* __restrict__ B,     // trans bf16 (DOUT x D row-major)
    float* __restrict__ out) {
  __shared__ ushort A_lds[4][16][264];   // 264 = 256 + 8 pad (bank spread)
  const int w = threadIdx.x >> 6;
  const int lane = threadIdx.x & 63;
  const int q0 = blockIdx.x * 64 + w * 16;

  const int base = offsets[q0];
  const int cnt = offsets[q0 + 16] - base;

  f32x4 acc = {0.f, 0.f, 0.f, 0.f};
  float rs = 0.f;
  int j = 0;
  int nbv = offsets[q0 + 1];
  int ar = base;  // absolute CSR row cursor

  auto flushq = [&](int jj) {
    const float inv = 1.0f / ((rs == 0.f) ? kEps : rs);
    union { ushort4 u; __hip_bfloat16 h[4]; } pk;
    pk.h[0] = __float2bfloat16(acc[0] * inv);
    pk.h[1] = __float2bfloat16(acc[1] * inv);
    pk.h[2] = __float2bfloat16(acc[2] * inv);
    pk.h[3] = __float2bfloat16(acc[3] * inv);
    *reinterpret_cast<ushort4*>(&A_lds[w][jj][lane * 4]) = pk.u;
    acc = (f32x4){0.f, 0.f, 0.f, 0.f};
    rs = 0.f;
  };

  int done = 0;
  while (done < cnt) {
    const int clen = min(64, cnt - done);
    const int idsv = (lane < clen) ? edge_ids[base + done + lane] : 0;
    const float evv = e[idsv];
    for (int bt = 0; bt < clen; bt += 8) {
      ushort4 u[8];
#pragma unroll
      for (int t = 0; t < 8; ++t) {
        if (bt + t < clen) {
          const int eg = __shfl(idsv, bt + t, 64);
          u[t] = *reinterpret_cast<const ushort4*>(wkey + (size_t)eg * kD + lane * 4);
        }
      }
#pragma unroll
      for (int t = 0; t < 8; ++t) {
        if (bt + t < clen) {
          while (ar >= nbv) {          // query j complete -> flush
            flushq(j);
            ++j;
            nbv = offsets[q0 + j + 1]; // j <= 15 here (ar < offsets[q0+16])
          }
          const float et = __shfl(evv, bt + t, 64);
          acc[0] += bf2f(u[t].x);
          acc[1] += bf2f(u[t].y);
          acc[2] += bf2f(u[t].z);
          acc[3] += bf2f(u[t].w);
          rs += et;
          ++ar;
        }
      }
    }
    done += clen;
  }
  while (j < 16) { flushq(j); ++j; }   // trailing (incl. empty) queries

  // ---- MFMA: out[q0..q0+16) = elu(A @ B^T) ----
  const int m = lane & 15;
  const int kb = (lane >> 4) * 8;
  f32x4 acc2[16];
#pragma unroll
  for (int nt = 0; nt < 16; ++nt) acc2[nt] = (f32x4){0.f, 0.f, 0.f, 0.f};

  for (int kt = 0; kt < kD; kt += 32) {
    const bf16x8 af = *reinterpret_cast<const bf16x8*>(&A_lds[w][m][kt + kb]);
#pragma unroll
    for (int nt = 0; nt < 16; ++nt) {
      const bf16x8 bf = *reinterpret_cast<const bf16x8*>(&B[(size_t)(nt * 16 + m) * kD + kt + kb]);
      acc2[nt] = __builtin_amdgcn_mfma_f32_16x16x32_bf16(af, bf, acc2[nt], 0, 0, 0);
    }
  }

#pragma unroll
  for (int nt = 0; nt < 16; ++nt) {
#pragma unroll
    for (int r = 0; r < 4; ++r) {
      const int row = q0 + (lane >> 4) * 4 + r;
      const float x = acc2[nt][r];
      out[(size_t)row * kDOUT + nt * 16 + m] = (x > 0.f) ? x : expm1f(x);
    }
  }
}

extern "C" void kernel_launch(void* const* d_in, const int* in_sizes, int n_in,
                              void* d_out, int out_size, void* d_ws, size_t ws_size,
                              hipStream_t stream) {
  // inputs: 0 key_list(int,E) [unused], 1 key_embed(f32,E*256), 2 query_list(int,E),
  //         3 query_embed(f32,E*256), 4 a(f32,256*512), 5 a_2(f32,256), 6 trans(f32,256*256)
  const float* key_embed = (const float*)d_in[1];
  const int* query_list = (const int*)d_in[2];
  const float* query_embed = (const float*)d_in[3];
  const float* a = (const float*)d_in[4];
  const float* a2 = (const float*)d_in[5];
  const float* trans = (const float*)d_in[6];
  float* out = (float*)d_out;

  // workspace (float units, 16B-aligned):
  // c[512] | count[NQ] | offsets[NQ+4] | cursor[NQ] | edge_ids[E] | e[E]
  // | wkey[E*256 ushort] | transb[256*256 ushort]
  float* ws = (float*)d_ws;
  float* c = ws;
  int* count = (int*)(ws + 512);
  int* offsets = count + kNQ;
  int* cursor = offsets + kNQ + 4;
  int* edge_ids = cursor + kNQ;
  float* e = (float*)(edge_ids + kE);
  ushort* wkey = (ushort*)(e + kE);                       // kE*256 bf16
  ushort* transb = (ushort*)((float*)wkey + (size_t)kE * (kD / 2));

  zero_kernel<<<kNQ / 4 / 256, 256, 0, stream>>>((int4*)count);
  compute_c_kernel<<<2, 256, 0, stream>>>(a, a2, c);
  cvt_trans_kernel<<<kDOUT * kD / 4 / 256, 256, 0, stream>>>(trans, transb);
  hist_kernel<<<kE / 4 / 256, 256, 0, stream>>>(query_list, count);
  scan_kernel<<<1, 1024, 0, stream>>>(count, offsets, cursor);
  scatter_kernel<<<kE / 256, 256, 0, stream>>>(query_list, cursor, edge_ids);
  edge_stream_kernel<<<kE / 4, 256, 0, stream>>>(key_embed, query_embed, c, wkey, e);
  gather_gemm_kernel<<<kNQ / 64, 256, 0, stream>>>(wkey, e, offsets, edge_ids, transb, out);
}

// Round 9
// 305.655 us; speedup vs baseline: 1.9800x; 1.2900x over previous
//
#include <hip/hip_runtime.h>
#include <hip/hip_bf16.h>
#include <math.h>

namespace {
constexpr int kD = 256;      // embed dim
constexpr int kDOUT = 256;   // out dim
constexpr int kNQ = 65536;   // num query nodes
constexpr int kE = 262144;   // edges
constexpr float kAlpha = 0.2f;
constexpr float kEps = 1e-12f;
}

typedef short bf16x8 __attribute__((ext_vector_type(8)));
typedef float f32x4 __attribute__((ext_vector_type(4)));
typedef unsigned short u16x8 __attribute__((ext_vector_type(8)));

static __device__ __forceinline__ float bf2f(unsigned short u) {
  union { unsigned int i; float f; } v;
  v.i = ((unsigned int)u) << 16;
  return v.f;
}

// c[j] = sum_k a[k][j] * a2[k]   (a is (DOUT, 2D) row-major; j in [0, 512))
__global__ void compute_c_kernel(const float* __restrict__ a,
                                 const float* __restrict__ a2,
                                 float* __restrict__ c) {
  const int j = blockIdx.x * blockDim.x + threadIdx.x;  // 0..511
  float s = 0.f;
#pragma unroll 8
  for (int k = 0; k < kDOUT; ++k) s = fmaf(a[k * (2 * kD) + j], a2[k], s);
  c[j] = s;
}

// zero count[NQ]
__global__ void zero_kernel(int4* __restrict__ p) {
  p[blockIdx.x * 256 + threadIdx.x] = int4{0, 0, 0, 0};
}

// trans (256x256 f32) -> bf16
__global__ void cvt_trans_kernel(const float* __restrict__ t, ushort* __restrict__ tb) {
  const int i = blockIdx.x * 256 + threadIdx.x;  // 4 elems each
  const float4 v = reinterpret_cast<const float4*>(t)[i];
  union { ushort4 u; __hip_bfloat16 h[4]; } p;
  p.h[0] = __float2bfloat16(v.x);
  p.h[1] = __float2bfloat16(v.y);
  p.h[2] = __float2bfloat16(v.z);
  p.h[3] = __float2bfloat16(v.w);
  reinterpret_cast<ushort4*>(tb)[i] = p.u;
}

// Single-block exclusive scan of count[NQ] -> offsets, cursor copy.
__global__ __launch_bounds__(1024) void scan_kernel(const int* __restrict__ count,
                                                    int* __restrict__ offsets,
                                                    int* __restrict__ cursor) {
  __shared__ int partial[1024];
  const int t = threadIdx.x;
  int4 loc[16];
#pragma unroll
  for (int i = 0; i < 16; ++i) loc[i] = reinterpret_cast<const int4*>(count)[t * 16 + i];
  int s = 0;
#pragma unroll
  for (int i = 0; i < 16; ++i) s += loc[i].x + loc[i].y + loc[i].z + loc[i].w;
  partial[t] = s;
  __syncthreads();
  for (int off = 1; off < 1024; off <<= 1) {
    int v = (t >= off) ? partial[t - off] : 0;
    __syncthreads();
    partial[t] += v;
    __syncthreads();
  }
  int run = partial[t] - s;
#pragma unroll
  for (int i = 0; i < 16; ++i) {
    const int4 v = loc[i];
    int4 o;
    o.x = run; run += v.x;
    o.y = run; run += v.y;
    o.z = run; run += v.z;
    o.w = run; run += v.w;
    reinterpret_cast<int4*>(offsets)[t * 16 + i] = o;
    reinterpret_cast<int4*>(cursor)[t * 16 + i] = o;
  }
  if (t == 1023) offsets[kNQ] = run;  // == E
}

// Scatter edge ids into CSR order.
__global__ __launch_bounds__(256) void scatter_kernel(const int* __restrict__ query_list,
                                                      int* __restrict__ cursor,
                                                      int* __restrict__ edge_ids) {
  const int edge = blockIdx.x * 256 + threadIdx.x;
  const int q = query_list[edge];
  const int pos = atomicAdd(&cursor[q], 1);
  edge_ids[pos] = edge;
}

// Pass 1: pure streaming + int histogram. One wave per edge (sequential read).
// ev = exp(-leaky(key.ck + query.cq)); write bf16(ev*key_row) in EDGE order
// (sequential) and e[edge]; count[q]++.
__global__ __launch_bounds__(256) void edge_stream_kernel(
    const float* __restrict__ key_embed,
    const float* __restrict__ query_embed,
    const int* __restrict__ qlist,
    const float* __restrict__ c,
    ushort* __restrict__ wkey,
    float* __restrict__ e_out,
    int* __restrict__ count) {
  const int edge = (blockIdx.x << 2) + (threadIdx.x >> 6);
  const int lane = threadIdx.x & 63;

  const float4 k4 = reinterpret_cast<const float4*>(key_embed)[(size_t)edge * (kD / 4) + lane];
  const float4 q4 = reinterpret_cast<const float4*>(query_embed)[(size_t)edge * (kD / 4) + lane];
  const float4 ck = reinterpret_cast<const float4*>(c)[lane];
  const float4 cq = reinterpret_cast<const float4*>(c)[64 + lane];

  float s = k4.x * ck.x + k4.y * ck.y + k4.z * ck.z + k4.w * ck.w
          + q4.x * cq.x + q4.y * cq.y + q4.z * cq.z + q4.w * cq.w;
#pragma unroll
  for (int off = 32; off > 0; off >>= 1) s += __shfl_xor(s, off, 64);

  const float p = (s > 0.f) ? s : kAlpha * s;   // leaky_relu
  const float ev = __expf(-p);

  union { ushort4 u; __hip_bfloat16 h[4]; } pk;
  pk.h[0] = __float2bfloat16(ev * k4.x);
  pk.h[1] = __float2bfloat16(ev * k4.y);
  pk.h[2] = __float2bfloat16(ev * k4.z);
  pk.h[3] = __float2bfloat16(ev * k4.w);
  *reinterpret_cast<ushort4*>(wkey + (size_t)edge * kD + lane * 4) = pk.u;
  if (lane == 0) {
    e_out[edge] = ev;
    atomicAdd(&count[qlist[edge]], 1);
  }
}

// Pass 2: one query per HALF-WAVE (32 lanes x ushort8 = 512B row).
// Up to 4 independent row loads in flight; accumulate f32; rs replicated
// per-lane (no reduction); normalize; coalesced bf16 write.
__global__ __launch_bounds__(256) void gather_kernel(
    const ushort* __restrict__ wkey,
    const float* __restrict__ e,
    const int* __restrict__ offsets,
    const int* __restrict__ edge_ids,
    ushort* __restrict__ accb) {
  const int wid = threadIdx.x >> 6;
  const int lane = threadIdx.x & 63;
  const int sub = lane >> 5;          // which half-wave
  const int hl = lane & 31;           // lane within half
  const int q = blockIdx.x * 8 + wid * 2 + sub;
  const int s0 = offsets[q], s1 = offsets[q + 1];

  float acc[8] = {};
  float rs = 0.f;

  for (int base = s0; base < s1; base += 32) {
    const int m = min(32, s1 - base);
    const int eid = (hl < m) ? edge_ids[base + hl] : 0;
    const float evl = (hl < m) ? e[eid] : 0.f;
    for (int i = 0; i < m; i += 4) {
      const int kc = min(4, m - i);
      u16x8 u[4];
      float evv[4];
#pragma unroll
      for (int t = 0; t < 4; ++t) {
        if (t < kc) {
          const int eg = __shfl(eid, (sub << 5) + i + t, 64);
          u[t] = *reinterpret_cast<const u16x8*>(wkey + (size_t)eg * kD + hl * 8);
          evv[t] = __shfl(evl, (sub << 5) + i + t, 64);
        }
      }
#pragma unroll
      for (int t = 0; t < 4; ++t) {
        if (t < kc) {
#pragma unroll
          for (int j = 0; j < 8; ++j) acc[j] += bf2f((unsigned short)u[t][j]);
          rs += evv[t];
        }
      }
    }
  }

  const float inv = 1.0f / ((rs == 0.f) ? kEps : rs);
  union { u16x8 u; __hip_bfloat16 h[8]; } p;
#pragma unroll
  for (int j = 0; j < 8; ++j) p.h[j] = __float2bfloat16(acc[j] * inv);
  *reinterpret_cast<u16x8*>(accb + (size_t)q * kD + hl * 8) = p.u;
}

// out = elu(A @ B^T).  A: (NQ,256) bf16 row-major (pre-normalized), B = trans bf16.
// One wave per 16-row strip, full N=256 in registers (16 n-tiles of 16x16x32 MFMA).
__global__ __launch_bounds__(256) void out_gemm_mfma_kernel(
    const ushort* __restrict__ A,
    const ushort* __restrict__ B,
    float* __restrict__ out) {
  const int wid = threadIdx.x >> 6;
  const int lane = threadIdx.x & 63;
  const int row0 = (blockIdx.x * 4 + wid) * 16;
  const int m = lane & 15;
  const int kb = (lane >> 4) * 8;

  f32x4 acc[16] = {};

  for (int kt = 0; kt < kD; kt += 32) {
    const bf16x8 af = *reinterpret_cast<const bf16x8*>(&A[(size_t)(row0 + m) * kD + kt + kb]);
#pragma unroll
    for (int nt = 0; nt < 16; ++nt) {
      const bf16x8 bf = *reinterpret_cast<const bf16x8*>(&B[(size_t)(nt * 16 + m) * kD + kt + kb]);
      acc[nt] = __builtin_amdgcn_mfma_f32_16x16x32_bf16(af, bf, acc[nt], 0, 0, 0);
    }
  }

#pragma unroll
  for (int nt = 0; nt < 16; ++nt) {
#pragma unroll
    for (int r = 0; r < 4; ++r) {
      const int row = row0 + (lane >> 4) * 4 + r;
      const int col = nt * 16 + (lane & 15);
      const float x = acc[nt][r];
      out[(size_t)row * kDOUT + col] = (x > 0.f) ? x : expm1f(x);
    }
  }
}

extern "C" void kernel_launch(void* const* d_in, const int* in_sizes, int n_in,
                              void* d_out, int out_size, void* d_ws, size_t ws_size,
                              hipStream_t stream) {
  // inputs: 0 key_list(int,E) [unused], 1 key_embed(f32,E*256), 2 query_list(int,E),
  //         3 query_embed(f32,E*256), 4 a(f32,256*512), 5 a_2(f32,256), 6 trans(f32,256*256)
  const float* key_embed = (const float*)d_in[1];
  const int* query_list = (const int*)d_in[2];
  const float* query_embed = (const float*)d_in[3];
  const float* a = (const float*)d_in[4];
  const float* a2 = (const float*)d_in[5];
  const float* trans = (const float*)d_in[6];
  float* out = (float*)d_out;

  // workspace (float units, 16B-aligned):
  // c[512] | count[NQ] | offsets[NQ+4] | cursor[NQ] | edge_ids[E] | e[E]
  // | wkey[E*256 ushort] | accb[NQ*256 ushort] | transb[256*256 ushort]
  float* ws = (float*)d_ws;
  float* c = ws;
  int* count = (int*)(ws + 512);
  int* offsets = count + kNQ;
  int* cursor = offsets + kNQ + 4;
  int* edge_ids = cursor + kNQ;
  float* e = (float*)(edge_ids + kE);
  ushort* wkey = (ushort*)(e + kE);                               // kE*256 bf16
  ushort* accb = wkey + (size_t)kE * kD;                          // kNQ*256 bf16
  ushort* transb = accb + (size_t)kNQ * kD;                       // 256*256 bf16

  zero_kernel<<<kNQ / 4 / 256, 256, 0, stream>>>((int4*)count);
  compute_c_kernel<<<2, 256, 0, stream>>>(a, a2, c);
  cvt_trans_kernel<<<kDOUT * kD / 4 / 256, 256, 0, stream>>>(trans, transb);
  edge_stream_kernel<<<kE / 4, 256, 0, stream>>>(key_embed, query_embed, query_list, c,
                                                 wkey, e, count);
  scan_kernel<<<1, 1024, 0, stream>>>(count, offsets, cursor);
  scatter_kernel<<<kE / 256, 256, 0, stream>>>(query_list, cursor, edge_ids);
  gather_kernel<<<kNQ / 8, 256, 0, stream>>>(wkey, e, offsets, edge_ids, accb);
  out_gemm_mfma_kernel<<<kNQ / 64, 256, 0, stream>>>(accb, transb, out);
}